// Round 1
// baseline (641.245 us; speedup 1.0000x reference)
//
#include <hip/hip_runtime.h>

#define N_NODES 100000
#define N_EDGES 1600000
#define NFEAT 128
#define NHID 64
#define NOUT 32

// ---------------------------------------------------------------
// GEMM1: support[N,64] = x[N,128] @ W1[128,64]
// W1 (32KB) in LDS, 64 nodes per block, 4 nodes in flight.
// ---------------------------------------------------------------
__global__ __launch_bounds__(256) void gemm1_kernel(const float* __restrict__ x,
                                                    const float* __restrict__ W1,
                                                    float* __restrict__ support) {
    __shared__ float wlds[NFEAT * NHID];   // 32 KB
    __shared__ float xs[4][NFEAT];         // 2 KB
    const int tid = threadIdx.x;
    for (int i = tid; i < NFEAT * NHID; i += 256) wlds[i] = W1[i];

    const int col = tid & 63;
    const int nl  = tid >> 6;              // 0..3
    const int base = blockIdx.x * 64;

    for (int it = 0; it < 64; it += 4) {
        const int n0 = base + it;
        __syncthreads();
        {   // cooperative load of 4 rows (512 floats, 2 per thread), coalesced
            const int r  = tid >> 7, c = tid & 127;
            const int n  = n0 + r;
            xs[r][c] = (n < N_NODES) ? x[(size_t)n * NFEAT + c] : 0.f;
            const int r2 = (tid + 256) >> 7;
            const int n2 = n0 + r2;
            xs[r2][c] = (n2 < N_NODES) ? x[(size_t)n2 * NFEAT + c] : 0.f;
        }
        __syncthreads();
        const int n = n0 + nl;
        if (n < N_NODES) {
            float acc = 0.f;
#pragma unroll
            for (int k = 0; k < NFEAT; ++k)
                acc += xs[nl][k] * wlds[k * NHID + col];   // xs broadcast, wlds 2-way (free)
            support[(size_t)n * NHID + col] = acc;
        }
    }
}

// ---------------------------------------------------------------
// zero h (atomic target) — kernel so graph capture is trivially safe
// ---------------------------------------------------------------
__global__ __launch_bounds__(256) void zero_kernel(float* __restrict__ p, int n) {
    int i = blockIdx.x * 256 + threadIdx.x;
    if (i < n) p[i] = 0.f;
}

// ---------------------------------------------------------------
// SpMM1: h[dst[e], :64] += vals[e] * support[src[e], :64]
// one wave per edge; lane = feature. Per-edge scalars are
// lane-uniform loads (HW broadcast); gather/atomic fully coalesced.
// ---------------------------------------------------------------
__global__ __launch_bounds__(256) void spmm1_kernel(const float* __restrict__ vals,
                                                    const int* __restrict__ src,
                                                    const int* __restrict__ dst,
                                                    const float* __restrict__ dense,
                                                    float* __restrict__ out) {
    const int lane   = threadIdx.x & 63;
    int wid          = (blockIdx.x * 256 + threadIdx.x) >> 6;
    const int nwaves = (gridDim.x * 256) >> 6;
    for (int e = wid; e < N_EDGES; e += nwaves) {
        const float v = vals[e];
        const int   s = src[e];
        const int   d = dst[e];
        atomicAdd(&out[(size_t)d * NHID + lane], v * dense[(size_t)s * NHID + lane]);
    }
}

// ---------------------------------------------------------------
// GEMM2 (fused): s2[N,32] = relu(h[N,64] + b1) @ W2[64,32]
// ---------------------------------------------------------------
__global__ __launch_bounds__(256) void gemm2_kernel(const float* __restrict__ h,
                                                    const float* __restrict__ b1,
                                                    const float* __restrict__ W2,
                                                    float* __restrict__ s2) {
    __shared__ float wlds[NHID * NOUT];    // 8 KB
    __shared__ float bs[NHID];
    __shared__ float xs[8][NHID];          // 2 KB
    const int tid = threadIdx.x;
    for (int i = tid; i < NHID * NOUT; i += 256) wlds[i] = W2[i];
    if (tid < NHID) bs[tid] = b1[tid];

    const int col = tid & 31;
    const int nl  = tid >> 5;              // 0..7
    const int base = blockIdx.x * 128;

    for (int it = 0; it < 128; it += 8) {
        const int n0 = base + it;
        __syncthreads();
        {   // load 8 rows (512 floats), apply bias + relu on the way in
            const int r  = tid >> 6, c = tid & 63;
            const int n  = n0 + r;
            xs[r][c] = (n < N_NODES) ? fmaxf(h[(size_t)n * NHID + c] + bs[c], 0.f) : 0.f;
            const int r2 = (tid + 256) >> 6;
            const int n2 = n0 + r2;
            xs[r2][c] = (n2 < N_NODES) ? fmaxf(h[(size_t)n2 * NHID + c] + bs[c], 0.f) : 0.f;
        }
        __syncthreads();
        const int n = n0 + nl;
        if (n < N_NODES) {
            float acc = 0.f;
#pragma unroll
            for (int k = 0; k < NHID; ++k)
                acc += xs[nl][k] * wlds[k * NOUT + col];
            s2[(size_t)n * NOUT + col] = acc;
        }
    }
}

// ---------------------------------------------------------------
// init out with b2 broadcast (so SpMM2 atomics land on top of bias)
// ---------------------------------------------------------------
__global__ __launch_bounds__(256) void init_out_kernel(const float* __restrict__ b2,
                                                       float* __restrict__ out) {
    int i = blockIdx.x * 256 + threadIdx.x;
    if (i < N_NODES * NOUT) out[i] = b2[i & 31];
}

// ---------------------------------------------------------------
// SpMM2: out[dst[e], :32] += vals[e] * s2[src[e], :32]
// one 32-lane half-wave per edge.
// ---------------------------------------------------------------
__global__ __launch_bounds__(256) void spmm2_kernel(const float* __restrict__ vals,
                                                    const int* __restrict__ src,
                                                    const int* __restrict__ dst,
                                                    const float* __restrict__ dense,
                                                    float* __restrict__ out) {
    const int lane    = threadIdx.x & 31;
    int gid           = (blockIdx.x * 256 + threadIdx.x) >> 5;
    const int ngroups = (gridDim.x * 256) >> 5;
    for (int e = gid; e < N_EDGES; e += ngroups) {
        const float v = vals[e];
        const int   s = src[e];
        const int   d = dst[e];
        atomicAdd(&out[(size_t)d * NOUT + lane], v * dense[(size_t)s * NOUT + lane]);
    }
}

extern "C" void kernel_launch(void* const* d_in, const int* in_sizes, int n_in,
                              void* d_out, int out_size, void* d_ws, size_t ws_size,
                              hipStream_t stream) {
    const float* x        = (const float*)d_in[0];
    const float* adj_vals = (const float*)d_in[1];
    const float* W1       = (const float*)d_in[2];
    const float* b1       = (const float*)d_in[3];
    const float* W2       = (const float*)d_in[4];
    const float* b2       = (const float*)d_in[5];
    const int*   esrc     = (const int*)d_in[6];
    const int*   edst     = (const int*)d_in[7];
    float*       out      = (float*)d_out;

    // workspace layout: [support: N*64] [h: N*64]; s2 reuses support region.
    float* support = (float*)d_ws;
    float* h       = support + (size_t)N_NODES * NHID;

    // 1. support = x @ W1
    gemm1_kernel<<<(N_NODES + 63) / 64, 256, 0, stream>>>(x, W1, support);

    // 2. h = 0 (atomic accumulation target; ws is NOT re-poisoned between replays)
    zero_kernel<<<(N_NODES * NHID + 255) / 256, 256, 0, stream>>>(h, N_NODES * NHID);

    // 3. h[dst] += val * support[src]
    spmm1_kernel<<<4096, 256, 0, stream>>>(adj_vals, esrc, edst, support, h);

    // 4. s2 = relu(h + b1) @ W2   (s2 overwrites support region)
    gemm2_kernel<<<(N_NODES + 127) / 128, 256, 0, stream>>>(h, b1, W2, support);

    // 5. out = b2 (broadcast)
    init_out_kernel<<<(N_NODES * NOUT + 255) / 256, 256, 0, stream>>>(b2, out);

    // 6. out[dst] += val * s2[src]
    spmm2_kernel<<<4096, 256, 0, stream>>>(adj_vals, esrc, edst, support, out);
}

// Round 2
// 486.369 us; speedup vs baseline: 1.3184x; 1.3184x over previous
//
#include <hip/hip_runtime.h>

#define N_NODES 100000
#define N_EDGES 1600000
#define NFEAT 128
#define NHID 64
#define NOUT 32

// ---------------------------------------------------------------
// GEMM1: support[N,64] = x[N,128] @ W1[128,64]
// ---------------------------------------------------------------
__global__ __launch_bounds__(256) void gemm1_kernel(const float* __restrict__ x,
                                                    const float* __restrict__ W1,
                                                    float* __restrict__ support) {
    __shared__ float wlds[NFEAT * NHID];   // 32 KB
    __shared__ float xs[4][NFEAT];         // 2 KB
    const int tid = threadIdx.x;
    for (int i = tid; i < NFEAT * NHID; i += 256) wlds[i] = W1[i];

    const int col = tid & 63;
    const int nl  = tid >> 6;              // 0..3
    const int base = blockIdx.x * 64;

    for (int it = 0; it < 64; it += 4) {
        const int n0 = base + it;
        __syncthreads();
        {
            const int r  = tid >> 7, c = tid & 127;
            const int n  = n0 + r;
            xs[r][c] = (n < N_NODES) ? x[(size_t)n * NFEAT + c] : 0.f;
            const int r2 = (tid + 256) >> 7;
            const int n2 = n0 + r2;
            xs[r2][c] = (n2 < N_NODES) ? x[(size_t)n2 * NFEAT + c] : 0.f;
        }
        __syncthreads();
        const int n = n0 + nl;
        if (n < N_NODES) {
            float acc = 0.f;
#pragma unroll
            for (int k = 0; k < NFEAT; ++k)
                acc += xs[nl][k] * wlds[k * NHID + col];
            support[(size_t)n * NHID + col] = acc;
        }
    }
}

// ---------------------------------------------------------------
// CSR build: zero counts -> histogram -> scan(3) -> scatter
// ---------------------------------------------------------------
__global__ __launch_bounds__(256) void zero_counts_kernel(int* __restrict__ counts) {
    int i = blockIdx.x * 256 + threadIdx.x;
    if (i < N_NODES) counts[i] = 0;
}

__global__ __launch_bounds__(256) void hist_kernel(const int* __restrict__ dst,
                                                   int* __restrict__ counts) {
    int e = blockIdx.x * 256 + threadIdx.x;
    if (e < N_EDGES) atomicAdd(&counts[dst[e]], 1);
}

// scan1: each block scans 1024 counts (4/thread), writes local exclusive scan + block sum
__global__ __launch_bounds__(256) void scan1_kernel(const int* __restrict__ counts,
                                                    int* __restrict__ offs,
                                                    int* __restrict__ blockSums) {
    __shared__ int lds[256];
    const int tid = threadIdx.x;
    const int base = blockIdx.x * 1024 + tid * 4;
    int v0 = (base + 0 < N_NODES) ? counts[base + 0] : 0;
    int v1 = (base + 1 < N_NODES) ? counts[base + 1] : 0;
    int v2 = (base + 2 < N_NODES) ? counts[base + 2] : 0;
    int v3 = (base + 3 < N_NODES) ? counts[base + 3] : 0;
    int tsum = v0 + v1 + v2 + v3;
    lds[tid] = tsum;
    __syncthreads();
    int val = tsum;
    for (int off = 1; off < 256; off <<= 1) {
        int add = (tid >= off) ? lds[tid - off] : 0;
        __syncthreads();
        val += add;
        lds[tid] = val;
        __syncthreads();
    }
    int excl = val - tsum;
    if (tid == 255) blockSums[blockIdx.x] = val;
    if (base + 0 < N_NODES) offs[base + 0] = excl;
    if (base + 1 < N_NODES) offs[base + 1] = excl + v0;
    if (base + 2 < N_NODES) offs[base + 2] = excl + v0 + v1;
    if (base + 3 < N_NODES) offs[base + 3] = excl + v0 + v1 + v2;
}

// scan2: single block, exclusive scan of the (<=128) block sums, in place
__global__ __launch_bounds__(128) void scan2_kernel(int* __restrict__ blockSums, int nb) {
    __shared__ int lds[128];
    const int tid = threadIdx.x;
    int v = (tid < nb) ? blockSums[tid] : 0;
    lds[tid] = v;
    __syncthreads();
    int val = v;
    for (int off = 1; off < 128; off <<= 1) {
        int add = (tid >= off) ? lds[tid - off] : 0;
        __syncthreads();
        val += add;
        lds[tid] = val;
        __syncthreads();
    }
    if (tid < nb) blockSums[tid] = val - v;   // exclusive
}

// scan3: add block offsets; also init cursor copy and the sentinel
__global__ __launch_bounds__(256) void scan3_kernel(int* __restrict__ offs,
                                                    const int* __restrict__ blockSums,
                                                    int* __restrict__ cursor) {
    int i = blockIdx.x * 256 + threadIdx.x;
    if (i < N_NODES) {
        int v = offs[i] + blockSums[i >> 10];
        offs[i] = v;
        cursor[i] = v;
    }
    if (i == 0) offs[N_NODES] = N_EDGES;
}

__global__ __launch_bounds__(256) void scatter_kernel(const float* __restrict__ vals,
                                                      const int* __restrict__ src,
                                                      const int* __restrict__ dst,
                                                      int* __restrict__ cursor,
                                                      int* __restrict__ ssrc,
                                                      float* __restrict__ sval) {
    int e = blockIdx.x * 256 + threadIdx.x;
    if (e < N_EDGES) {
        int d = dst[e];
        int pos = atomicAdd(&cursor[d], 1);
        ssrc[pos] = src[e];
        sval[pos] = vals[e];
    }
}

// ---------------------------------------------------------------
// SpMM1 (CSR): h[d,:] = relu( sum_e val*support[src,:] + b1 )
// one wave per node, lane = feature; no atomics, one store per row.
// ---------------------------------------------------------------
__global__ __launch_bounds__(256) void spmm1_csr_kernel(const int* __restrict__ offs,
                                                        const int* __restrict__ ssrc,
                                                        const float* __restrict__ sval,
                                                        const float* __restrict__ dense,
                                                        const float* __restrict__ b1,
                                                        float* __restrict__ h) {
    const int lane = threadIdx.x & 63;
    const int d = (blockIdx.x * 256 + threadIdx.x) >> 6;
    if (d >= N_NODES) return;
    const int start = offs[d], end = offs[d + 1];
    float acc0 = 0.f, acc1 = 0.f;
    int e = start;
    for (; e + 1 < end; e += 2) {
        float v0 = sval[e],     v1 = sval[e + 1];
        int   s0 = ssrc[e],     s1 = ssrc[e + 1];
        acc0 += v0 * dense[(size_t)s0 * NHID + lane];
        acc1 += v1 * dense[(size_t)s1 * NHID + lane];
    }
    if (e < end) acc0 += sval[e] * dense[(size_t)ssrc[e] * NHID + lane];
    h[(size_t)d * NHID + lane] = fmaxf(acc0 + acc1 + b1[lane], 0.f);
}

// ---------------------------------------------------------------
// GEMM2: s2[N,32] = h[N,64] @ W2[64,32]   (h already biased+relu'd)
// ---------------------------------------------------------------
__global__ __launch_bounds__(256) void gemm2_kernel(const float* __restrict__ h,
                                                    const float* __restrict__ W2,
                                                    float* __restrict__ s2) {
    __shared__ float wlds[NHID * NOUT];    // 8 KB
    __shared__ float xs[8][NHID];
    const int tid = threadIdx.x;
    for (int i = tid; i < NHID * NOUT; i += 256) wlds[i] = W2[i];

    const int col = tid & 31;
    const int nl  = tid >> 5;              // 0..7
    const int base = blockIdx.x * 128;

    for (int it = 0; it < 128; it += 8) {
        const int n0 = base + it;
        __syncthreads();
        {
            const int r  = tid >> 6, c = tid & 63;
            const int n  = n0 + r;
            xs[r][c] = (n < N_NODES) ? h[(size_t)n * NHID + c] : 0.f;
            const int r2 = (tid + 256) >> 6;
            const int n2 = n0 + r2;
            xs[r2][c] = (n2 < N_NODES) ? h[(size_t)n2 * NHID + c] : 0.f;
        }
        __syncthreads();
        const int n = n0 + nl;
        if (n < N_NODES) {
            float acc = 0.f;
#pragma unroll
            for (int k = 0; k < NHID; ++k)
                acc += xs[nl][k] * wlds[k * NOUT + col];
            s2[(size_t)n * NOUT + col] = acc;
        }
    }
}

// ---------------------------------------------------------------
// SpMM2 (CSR): out[d,:] = sum_e val*s2[src,:] + b2
// one wave per node; the two 32-lane halves split edges by parity.
// ---------------------------------------------------------------
__global__ __launch_bounds__(256) void spmm2_csr_kernel(const int* __restrict__ offs,
                                                        const int* __restrict__ ssrc,
                                                        const float* __restrict__ sval,
                                                        const float* __restrict__ dense,
                                                        const float* __restrict__ b2,
                                                        float* __restrict__ out) {
    const int lane = threadIdx.x & 63;
    const int half = lane >> 5, l32 = lane & 31;
    const int d = (blockIdx.x * 256 + threadIdx.x) >> 6;
    if (d >= N_NODES) return;
    const int start = offs[d], end = offs[d + 1];
    float acc = 0.f;
    for (int e = start + half; e < end; e += 2)
        acc += sval[e] * dense[(size_t)ssrc[e] * NOUT + l32];
    acc += __shfl_xor(acc, 32, 64);
    if (half == 0) out[(size_t)d * NOUT + l32] = acc + b2[l32];
}

extern "C" void kernel_launch(void* const* d_in, const int* in_sizes, int n_in,
                              void* d_out, int out_size, void* d_ws, size_t ws_size,
                              hipStream_t stream) {
    const float* x        = (const float*)d_in[0];
    const float* adj_vals = (const float*)d_in[1];
    const float* W1       = (const float*)d_in[2];
    const float* b1       = (const float*)d_in[3];
    const float* W2       = (const float*)d_in[4];
    const float* b2       = (const float*)d_in[5];
    const int*   esrc     = (const int*)d_in[6];
    const int*   edst     = (const int*)d_in[7];
    float*       out      = (float*)d_out;

    // workspace layout (all fully rewritten every call):
    float* support  = (float*)d_ws;                       // 6.4M f
    float* h        = support + (size_t)N_NODES * NHID;   // 6.4M f
    float* sval     = h + (size_t)N_NODES * NHID;         // 1.6M f
    int*   ssrc     = (int*)(sval + N_EDGES);             // 1.6M i
    int*   offs     = ssrc + N_EDGES;                     // N+1
    int*   cursor   = offs + (N_NODES + 1);               // N
    int*   counts   = cursor + N_NODES;                   // N
    int*   blockSums = counts + N_NODES;                  // 98

    const int NB_SCAN = (N_NODES + 1023) / 1024;          // 98

    // 1. support = x @ W1
    gemm1_kernel<<<(N_NODES + 63) / 64, 256, 0, stream>>>(x, W1, support);

    // 2. CSR build (shared by both SpMMs)
    zero_counts_kernel<<<(N_NODES + 255) / 256, 256, 0, stream>>>(counts);
    hist_kernel<<<(N_EDGES + 255) / 256, 256, 0, stream>>>(edst, counts);
    scan1_kernel<<<NB_SCAN, 256, 0, stream>>>(counts, offs, blockSums);
    scan2_kernel<<<1, 128, 0, stream>>>(blockSums, NB_SCAN);
    scan3_kernel<<<(N_NODES + 255) / 256, 256, 0, stream>>>(offs, blockSums, cursor);
    scatter_kernel<<<(N_EDGES + 255) / 256, 256, 0, stream>>>(adj_vals, esrc, edst,
                                                              cursor, ssrc, sval);

    // 3. h = relu(A @ support + b1)
    spmm1_csr_kernel<<<(N_NODES * 64 + 255) / 256, 256, 0, stream>>>(offs, ssrc, sval,
                                                                     support, b1, h);

    // 4. s2 = h @ W2  (into support region)
    gemm2_kernel<<<(N_NODES + 127) / 128, 256, 0, stream>>>(h, W2, support);

    // 5. out = A @ s2 + b2
    spmm2_csr_kernel<<<(N_NODES * 64 + 255) / 256, 256, 0, stream>>>(offs, ssrc, sval,
                                                                     support, b2, out);
}